// Round 6
// baseline (1421.047 us; speedup 1.0000x reference)
//
#include <hip/hip_runtime.h>

typedef unsigned short u16;
typedef unsigned long long u64;
typedef short v8s __attribute__((ext_vector_type(8)));   // 8 x bf16 (guide §3)
typedef float v4f __attribute__((ext_vector_type(4)));

__device__ __forceinline__ u16 f2bf(float x) {
    union { float f; unsigned u; } v; v.f = x;
    unsigned r = v.u + 0x7fffu + ((v.u >> 16) & 1u);   // RNE
    return (u16)(r >> 16);
}

// fast tanh: 1 - 2/(exp2(2*log2e*x)+1). Saturates exactly (+inf->1, 0->-1);
// err ~1e-6 << bf16 rounding. ~6 VALU/TRANS inst vs ocml tanhf's 20+.
__device__ __forceinline__ float tanh_fast(float x) {
    float e = __builtin_amdgcn_exp2f(x * 2.88539008177793f);   // 2*log2(e)
    return __builtin_fmaf(-2.0f, __builtin_amdgcn_rcpf(e + 1.0f), 1.0f);
}

// ---------------------------------------------------------------------------
// K1: transpose+convert the three 1024x1024 fp32 weights to bf16 W^T[n][k]
// ---------------------------------------------------------------------------
__global__ __launch_bounds__(256) void convert_w(
    const float* __restrict__ Wi, const float* __restrict__ Wh,
    const float* __restrict__ Wo, u16* __restrict__ wi_t,
    u16* __restrict__ wh_t, u16* __restrict__ wo_t) {
    const float* src; u16* dst;
    if (blockIdx.y == 0)      { src = Wi; dst = wi_t; }
    else if (blockIdx.y == 1) { src = Wh; dst = wh_t; }
    else                      { src = Wo; dst = wo_t; }
    int k0 = (blockIdx.x & 31) * 32;
    int n0 = (blockIdx.x >> 5) * 32;
    __shared__ float tile[32][33];
    int t = threadIdx.x;
    {
        int kl = t >> 3, nl4 = (t & 7) * 4;
        float4 v = *(const float4*)(src + (size_t)(k0 + kl) * 1024 + n0 + nl4);
        tile[kl][nl4 + 0] = v.x; tile[kl][nl4 + 1] = v.y;
        tile[kl][nl4 + 2] = v.z; tile[kl][nl4 + 3] = v.w;
    }
    __syncthreads();
    {
        int nl = t >> 3, kl4 = (t & 7) * 4;
        ushort4 o;
        o.x = f2bf(tile[kl4 + 0][nl]); o.y = f2bf(tile[kl4 + 1][nl]);
        o.z = f2bf(tile[kl4 + 2][nl]); o.w = f2bf(tile[kl4 + 3][nl]);
        *(ushort4*)(dst + (size_t)(n0 + nl) * 1024 + k0 + kl4) = o;
    }
}

// ---------------------------------------------------------------------------
// K2: gather embedding rows -> bf16 A matrix, row r = t*64 + b
// ---------------------------------------------------------------------------
__global__ __launch_bounds__(256) void gather_emb(
    const int* __restrict__ input, const float* __restrict__ emb,
    u16* __restrict__ Aemb) {
    int r = blockIdx.x * 4 + (threadIdx.x >> 6);
    int lane = threadIdx.x & 63;
    int b = r & 63, t = r >> 6;
    int idx = input[b * 256 + t];          // input is [B=64][T=256]
    const float* s = emb + (size_t)idx * 1024;
    u16* d = Aemb + (size_t)r * 1024;
#pragma unroll
    for (int i = 0; i < 4; i++) {
        float4 v = *(const float4*)(s + i * 256 + lane * 4);
        ushort4 o;
        o.x = f2bf(v.x); o.y = f2bf(v.y); o.z = f2bf(v.z); o.w = f2bf(v.w);
        *(ushort4*)(d + i * 256 + lane * 4) = o;
    }
}

// ---------------------------------------------------------------------------
// K3/K5: bf16 GEMM  out[map(r)][n] = sum_k A[r][k]*Bt[n][k] + bias[n]
// (unchanged — validated)
// ---------------------------------------------------------------------------
__global__ __launch_bounds__(256) void gemm_bias(
    const u16* __restrict__ A, const u16* __restrict__ Bt,
    const float* __restrict__ bias, float* __restrict__ out, int mode) {
    __shared__ u16 lA[128 * 40];
    __shared__ u16 lB[128 * 40];
    const int tid = threadIdx.x;
    const int w = tid >> 6, lane = tid & 63;
    const int l15 = lane & 15, quad = lane >> 4;
    const int m0 = blockIdx.x * 128, n0 = blockIdx.y * 128;
    const int wm = (w & 1) * 64, wn = (w >> 1) * 64;
    const int srow = tid >> 1, shalf = tid & 1;
    const u16* gA = A + (size_t)(m0 + srow) * 1024 + shalf * 16;
    const u16* gB = Bt + (size_t)(n0 + srow) * 1024 + shalf * 16;
    v4f zero = {0.f, 0.f, 0.f, 0.f};
    v4f acc[4][4];
#pragma unroll
    for (int i = 0; i < 4; i++)
#pragma unroll
        for (int j = 0; j < 4; j++) acc[i][j] = zero;

    uint4 ra0 = *(const uint4*)gA;
    uint4 ra1 = *(const uint4*)(gA + 8);
    uint4 rb0 = *(const uint4*)gB;
    uint4 rb1 = *(const uint4*)(gB + 8);

    for (int kt = 0; kt < 32; ++kt) {
        __syncthreads();
        *(uint4*)(lA + srow * 40 + shalf * 16) = ra0;
        *(uint4*)(lA + srow * 40 + shalf * 16 + 8) = ra1;
        *(uint4*)(lB + srow * 40 + shalf * 16) = rb0;
        *(uint4*)(lB + srow * 40 + shalf * 16 + 8) = rb1;
        __syncthreads();
        if (kt < 31) {   // prefetch next k-tile while MFMAs run
            const u16* pA = gA + (kt + 1) * 32;
            const u16* pB = gB + (kt + 1) * 32;
            ra0 = *(const uint4*)pA; ra1 = *(const uint4*)(pA + 8);
            rb0 = *(const uint4*)pB; rb1 = *(const uint4*)(pB + 8);
        }
        v8s af[4], bfv[4];
#pragma unroll
        for (int mt = 0; mt < 4; mt++)
            af[mt] = *(const v8s*)(lA + (wm + mt * 16 + l15) * 40 + quad * 8);
#pragma unroll
        for (int nt = 0; nt < 4; nt++)
            bfv[nt] = *(const v8s*)(lB + (wn + nt * 16 + l15) * 40 + quad * 8);
#pragma unroll
        for (int mt = 0; mt < 4; mt++)
#pragma unroll
            for (int nt = 0; nt < 4; nt++)
                acc[mt][nt] = __builtin_amdgcn_mfma_f32_16x16x32_bf16(
                    af[mt], bfv[nt], acc[mt][nt], 0, 0, 0);
    }
#pragma unroll
    for (int nt = 0; nt < 4; nt++) {
        int coln = n0 + wn + nt * 16 + l15;
        float bv = bias[coln];
#pragma unroll
        for (int mt = 0; mt < 4; mt++) {
            int rbase = m0 + wm + mt * 16 + quad * 4;
#pragma unroll
            for (int r = 0; r < 4; r++) {
                int row = rbase + r;
                int orow = mode ? ((row & 63) * 256 + (row >> 6)) : row;
                out[(size_t)orow * 1024 + coln] = acc[mt][nt][r] + bv;
            }
        }
    }
}

// ---------------------------------------------------------------------------
// K4: persistent recurrence — r3 TAG-IN-DATA protocol + vmcnt-aware schedule.
// Geometry/protocol byte-identical to r3 (64 WGs x 256 thr, 4 groups x 16
// producers, hot 2-slab parity buffer, tag bit14 in each atomic u64).
// r5 lesson: fan-in is not the lever. New in r6 — the SCHEDULE:
//   vmcnt retires IN ISSUE ORDER, so any load/store issued before the polls
//   gates the tag check on its own (HBM) latency. Fixes:
//   (a) polls are the OLDEST vmem ops of each iteration;
//   (b) ix is software-pipelined one step ahead (issued post-stage, ~1300cy
//       before the next check -> retired, never gating);
//   (c) h_all stores of step t-1 deferred to after step t's tag-check
//       (acks age out during stage+MFMA, off the poll path);
//   (d) tanh_fast replaces ocml tanhf on the producer critical path.
// One barrier/step (LDS dbuf 2x32KB, XOR swizzle). WAW slab safety by the
// data dependency chain (r3 comment). h^0 = 0 => t=0 skips the matmul.
// ---------------------------------------------------------------------------
__global__ __launch_bounds__(256, 1) void rnn_step_all(
    const u16* __restrict__ wh_t, const float* __restrict__ bh,
    const float* __restrict__ ix, u64* __restrict__ h_buf64,  // [2][64][256] u64
    u16* __restrict__ h_all, float* __restrict__ out_tail) {
    const int tid = threadIdx.x, w = tid >> 6, lane = tid & 63;
    const int g = blockIdx.x, gb = g & 3, gc = g >> 2;
    const int quad = lane >> 4, l15 = lane & 15;
    const int col = gc * 64 + w * 16 + l15;
    __shared__ u16 hts[2][16 * 1024];   // 64KB dbuf, XOR-swizzled rows

    // B fragments resident in registers: Wh^T[col][k] — 128 VGPRs
    v8s bfr[32];
#pragma unroll
    for (int kc = 0; kc < 32; kc++)
        bfr[kc] = *(const v8s*)(wh_t + (size_t)col * 1024 + kc * 32 + quad * 8);
    const float bhv = bh[col];
    const int mrow0 = gb * 16 + quad * 4;   // this lane's 4 output batch rows
    const int srow = tid >> 4, sseg = tid & 15;   // staging role: 16 thr/row

    // ix(0) prefetch (before the loop; retired long before any poll)
    float ixc[4], ixn[4];
    {
        const float* ixp = ix + (size_t)mrow0 * 1024 + col;
#pragma unroll
        for (int r = 0; r < 4; r++) ixc[r] = ixp[(size_t)r * 1024];
    }
    u64 qs[4];        // step t's packed h words (clean)
    u64 qs_prev[4];   // step t-1's packed h words, h_all store deferred
    float hv[4];

    for (int t = 0; t < 256; t++) {
        char* htile = (char*)hts[t & 1];
        if (t > 0) {
            const u64 e = (u64)((t >> 1) & 1);   // expected tag for h^t
            const u64* hsrc =
                h_buf64 + (size_t)(t & 1) * 16384 + (gb * 16 + srow) * 256;
            // (a) POLLS FIRST — oldest vmem ops of this iteration
            u64 tmp[16];
#pragma unroll
            for (int i = 0; i < 16; i++)
                tmp[i] = __hip_atomic_load(hsrc + sseg + i * 16,
                                           __ATOMIC_RELAXED,
                                           __HIP_MEMORY_SCOPE_AGENT);
            // tag check: per-word re-poll of laggards, batched per pass
            int guard = 0; bool again = true;
            while (again) {
                again = false;
#pragma unroll
                for (int i = 0; i < 16; i++)
                    if (((tmp[i] >> 14) & 1ull) != e) {
                        tmp[i] = __hip_atomic_load(hsrc + sseg + i * 16,
                                                   __ATOMIC_RELAXED,
                                                   __HIP_MEMORY_SCOPE_AGENT);
                        again = true;
                    }
                if (++guard > (1 << 20)) break;   // hang safety only
            }
            // (c) deferred h_all store for step t-1 — issued post-check, its
            // ack ages out during stage+MFMA, never gating a poll
            {
                u64* hall64 = (u64*)(h_all + (size_t)(t - 1) * 65536);
                if ((lane & 3) == 0) {
#pragma unroll
                    for (int r = 0; r < 4; r++)
                        hall64[(mrow0 + r) * 256 + (col >> 2)] = qs_prev[r];
                }
            }
            // stage into LDS (strip tag, XOR swizzle)
#pragma unroll
            for (int i = 0; i < 16; i++) {
                u64 v = tmp[i] & ~0x4000ull;
                int wbyte = ((sseg + i * 16) * 8) ^ ((srow & 7) << 4);
                *(u64*)(htile + srow * 2048 + wbyte) = v;
            }
        }
        // (b) ix(t+1) prefetch — issued here so it retires before the NEXT
        // iteration's polls (age ~= MFMA+epilogue+store+poll RT > HBM lat)
        if (t < 255) {
            const float* ixp = ix + ((size_t)(t + 1) * 64 + mrow0) * 1024 + col;
#pragma unroll
            for (int r = 0; r < 4; r++) ixn[r] = ixp[(size_t)r * 1024];
        }
        __syncthreads();   // the ONLY barrier per step (dbuf LDS)
        v4f acc[4];
#pragma unroll
        for (int j = 0; j < 4; j++) acc[j] = (v4f){0.f, 0.f, 0.f, 0.f};
        if (t > 0) {
#pragma unroll
            for (int kc = 0; kc < 32; kc++) {
                int rbyte = (kc * 64 + quad * 16) ^ ((l15 & 7) << 4);
                v8s a = *(const v8s*)(htile + l15 * 2048 + rbyte);
                acc[kc & 3] = __builtin_amdgcn_mfma_f32_16x16x32_bf16(
                    a, bfr[kc], acc[kc & 3], 0, 0, 0);
            }
        }
        // epilogue: h = tanh(acc + ix_t + bh)  (d: fast tanh, ~6 inst/elem)
        u16 hb[4];
#pragma unroll
        for (int r = 0; r < 4; r++) {
            float pre = acc[0][r] + acc[1][r] + acc[2][r] + acc[3][r] +
                        ixc[r] + bhv;
            hv[r] = tanh_fast(pre);
            hb[r] = f2bf(hv[r]);
        }
        // pack 4 adjacent cols -> u64 via DPP shuffles; store TAGGED word to
        // the parity slab (data == ready flag); clean copy kept in qs[]
        const u64 tagbit = (u64)(((t + 1) >> 1) & 1) << 14;  // tag of h^{t+1}
        u64* hdst = h_buf64 + (size_t)((t + 1) & 1) * 16384;
#pragma unroll
        for (int r = 0; r < 4; r++) {
            unsigned own = hb[r];
            unsigned other = __shfl_xor(own, 1);        // col^1 partner
            unsigned p = own | (other << 16);           // cols [c, c+1]
            unsigned p2 = __shfl_xor(p, 2);             // cols [c+2, c+3]
            qs[r] = (u64)p | ((u64)p2 << 32);
            if ((lane & 3) == 0)
                __hip_atomic_store(hdst + (mrow0 + r) * 256 + (col >> 2),
                                   qs[r] | tagbit, __ATOMIC_RELAXED,
                                   __HIP_MEMORY_SCOPE_AGENT);
        }
        // rotate pipelined state
#pragma unroll
        for (int r = 0; r < 4; r++) { qs_prev[r] = qs[r]; ixc[r] = ixn[r]; }
    }
    // final h_all slab (t=255) + final hidden state
    {
        u64* hall64 = (u64*)(h_all + 255ull * 65536);
#pragma unroll
        for (int r = 0; r < 4; r++) {
            if ((lane & 3) == 0)
                hall64[(mrow0 + r) * 256 + (col >> 2)] = qs_prev[r];
            out_tail[(mrow0 + r) * 1024 + col] = hv[r];
        }
    }
}

// ---------------------------------------------------------------------------
// Workspace map (bytes):  [0,2M) Wi^T  [2M,4M) Wh^T  [4M,6M) Wo^T
// [6M,38M) Aemb bf16 (reused as h_all in phases 2/3)
// [38M,+256K) h parity slabs (slab0 init 0x00, slab1 init 0xFF — tag protocol)
// ix (fp32 [T][B][H], 64MB) lives in d_out, consumed before phase 3 overwrites.
// ---------------------------------------------------------------------------
extern "C" void kernel_launch(void* const* d_in, const int* in_sizes, int n_in,
                              void* d_out, int out_size, void* d_ws,
                              size_t ws_size, hipStream_t stream) {
    const int*   input = (const int*)d_in[0];
    // d_in[1] = hidden (zeros by construction; t=0 path assumes h^0 = 0)
    const float* emb = (const float*)d_in[2];
    const float* Wi  = (const float*)d_in[3];
    const float* bi  = (const float*)d_in[4];
    const float* Wh  = (const float*)d_in[5];
    const float* bh  = (const float*)d_in[6];
    const float* Wo  = (const float*)d_in[7];
    const float* bo  = (const float*)d_in[8];
    float* out = (float*)d_out;
    char* ws = (char*)d_ws;

    u16* wi_t  = (u16*)(ws);
    u16* wh_t  = (u16*)(ws + (2ull << 20));
    u16* wo_t  = (u16*)(ws + (4ull << 20));
    u16* Aemb  = (u16*)(ws + (6ull << 20));            // 32MB, doubles as h_all
    u64* h_buf = (u64*)(ws + (38ull << 20));           // 256KB, [2][64][256] u64

    float* ix = out;                                   // [256][64][1024] fp32
    float* out_tail = out + 16777216ull;               // final hidden [64][1024]

    // tag-protocol slab init: slab0 tag0 (h^2 expects tag1 -> blocks),
    // slab1 tag1 (h^1 expects tag0 -> blocks)
    hipMemsetAsync(h_buf, 0x00, 131072, stream);
    hipMemsetAsync((char*)h_buf + 131072, 0xFF, 131072, stream);
    convert_w<<<dim3(1024, 3), 256, 0, stream>>>(Wi, Wh, Wo, wi_t, wh_t, wo_t);
    gather_emb<<<4096, 256, 0, stream>>>(input, emb, Aemb);
    gemm_bias<<<dim3(128, 8), 256, 0, stream>>>(Aemb, wi_t, bi, ix, 0);
    rnn_step_all<<<64, 256, 0, stream>>>(wh_t, bh, ix, h_buf, Aemb, out_tail);
    gemm_bias<<<dim3(128, 8), 256, 0, stream>>>(Aemb, wo_t, bo, out, 1);
}

// Round 7
// 1149.207 us; speedup vs baseline: 1.2365x; 1.2365x over previous
//
#include <hip/hip_runtime.h>

typedef unsigned short u16;
typedef unsigned long long u64;
typedef short v8s __attribute__((ext_vector_type(8)));   // 8 x bf16 (guide §3)
typedef float v4f __attribute__((ext_vector_type(4)));

__device__ __forceinline__ u16 f2bf(float x) {
    union { float f; unsigned u; } v; v.f = x;
    unsigned r = v.u + 0x7fffu + ((v.u >> 16) & 1u);   // RNE
    return (u16)(r >> 16);
}

// fast tanh: 1 - 2/(exp2(2*log2e*x)+1). Saturates exactly; err ~1e-6 << bf16
// rounding (validated r6: identical absmax). ~6 VALU/TRANS vs ocml's 20+.
__device__ __forceinline__ float tanh_fast(float x) {
    float e = __builtin_amdgcn_exp2f(x * 2.88539008177793f);   // 2*log2(e)
    return __builtin_fmaf(-2.0f, __builtin_amdgcn_rcpf(e + 1.0f), 1.0f);
}

// ---------------------------------------------------------------------------
// K1: transpose+convert the three 1024x1024 fp32 weights to bf16 W^T[n][k]
// ---------------------------------------------------------------------------
__global__ __launch_bounds__(256) void convert_w(
    const float* __restrict__ Wi, const float* __restrict__ Wh,
    const float* __restrict__ Wo, u16* __restrict__ wi_t,
    u16* __restrict__ wh_t, u16* __restrict__ wo_t) {
    const float* src; u16* dst;
    if (blockIdx.y == 0)      { src = Wi; dst = wi_t; }
    else if (blockIdx.y == 1) { src = Wh; dst = wh_t; }
    else                      { src = Wo; dst = wo_t; }
    int k0 = (blockIdx.x & 31) * 32;
    int n0 = (blockIdx.x >> 5) * 32;
    __shared__ float tile[32][33];
    int t = threadIdx.x;
    {
        int kl = t >> 3, nl4 = (t & 7) * 4;
        float4 v = *(const float4*)(src + (size_t)(k0 + kl) * 1024 + n0 + nl4);
        tile[kl][nl4 + 0] = v.x; tile[kl][nl4 + 1] = v.y;
        tile[kl][nl4 + 2] = v.z; tile[kl][nl4 + 3] = v.w;
    }
    __syncthreads();
    {
        int nl = t >> 3, kl4 = (t & 7) * 4;
        ushort4 o;
        o.x = f2bf(tile[kl4 + 0][nl]); o.y = f2bf(tile[kl4 + 1][nl]);
        o.z = f2bf(tile[kl4 + 2][nl]); o.w = f2bf(tile[kl4 + 3][nl]);
        *(ushort4*)(dst + (size_t)(n0 + nl) * 1024 + k0 + kl4) = o;
    }
}

// ---------------------------------------------------------------------------
// K2: gather embedding rows -> bf16 A matrix, row r = t*64 + b
// ---------------------------------------------------------------------------
__global__ __launch_bounds__(256) void gather_emb(
    const int* __restrict__ input, const float* __restrict__ emb,
    u16* __restrict__ Aemb) {
    int r = blockIdx.x * 4 + (threadIdx.x >> 6);
    int lane = threadIdx.x & 63;
    int b = r & 63, t = r >> 6;
    int idx = input[b * 256 + t];          // input is [B=64][T=256]
    const float* s = emb + (size_t)idx * 1024;
    u16* d = Aemb + (size_t)r * 1024;
#pragma unroll
    for (int i = 0; i < 4; i++) {
        float4 v = *(const float4*)(s + i * 256 + lane * 4);
        ushort4 o;
        o.x = f2bf(v.x); o.y = f2bf(v.y); o.z = f2bf(v.z); o.w = f2bf(v.w);
        *(ushort4*)(d + i * 256 + lane * 4) = o;
    }
}

// ---------------------------------------------------------------------------
// K3/K5: bf16 GEMM  out[map(r)][n] = sum_k A[r][k]*Bt[n][k] + bias[n]
// r7: staging rewritten m97-style — global_load_lds width=16 into LINEAR
// 128x32 LDS tiles (guide §5 ladder step 3: 517->874 TF at this tile size;
// m151: gload_lds 874 vs reg-staging 646 at 128²). The compiler never emits
// this itself (common-mistake #1). Stage latency between the two barriers is
// hidden by inter-block wave overlap (m114; 4 blocks/CU here). MFMA fragment
// reads come from linear rows (64B stride) — m97-level bank conflicts
// accepted, as measured. MFMA + bias + output remap unchanged (validated).
// ---------------------------------------------------------------------------
__global__ __launch_bounds__(256) void gemm_bias(
    const u16* __restrict__ A, const u16* __restrict__ Bt,
    const float* __restrict__ bias, float* __restrict__ out, int mode) {
    __shared__ u16 lA[128 * 32];
    __shared__ u16 lB[128 * 32];
    const int tid = threadIdx.x;
    const int w = tid >> 6, lane = tid & 63;
    const int l15 = lane & 15, quad = lane >> 4;
    const int m0 = blockIdx.x * 128, n0 = blockIdx.y * 128;
    const int wm = (w & 1) * 64, wn = (w >> 1) * 64;
    const u16* gA = A + (size_t)m0 * 1024;
    const u16* gB = Bt + (size_t)n0 * 1024;
    auto* ldsA = (__attribute__((address_space(3))) u16*)lA;
    auto* ldsB = (__attribute__((address_space(3))) u16*)lB;

    v4f zero = {0.f, 0.f, 0.f, 0.f};
    v4f acc[4][4];
#pragma unroll
    for (int i = 0; i < 4; i++)
#pragma unroll
        for (int j = 0; j < 4; j++) acc[i][j] = zero;

    for (int kt = 0; kt < 32; ++kt) {
        __syncthreads();   // prior MFMA reads of lA/lB complete
        // stage 2x8KB via async global->LDS, 16B/lane, wave-linear dest.
        // chunk index idx = (w*2+j)*64 + lane; row = idx>>2, 16B-chunk = idx&3.
        // lane0's lds ptr is the wave-uniform base; HW adds lane*16 (guide §5).
#pragma unroll
        for (int j = 0; j < 2; j++) {
            int idx = (w * 2 + j) * 64 + lane;
            int row = idx >> 2, ch = idx & 3;
            size_t goff = (size_t)row * 1024 + kt * 32 + ch * 8;
            __builtin_amdgcn_global_load_lds(
                (const __attribute__((address_space(1))) unsigned*)(gA + goff),
                (__attribute__((address_space(3))) unsigned*)(ldsA + idx * 8),
                16, 0, 0);
            __builtin_amdgcn_global_load_lds(
                (const __attribute__((address_space(1))) unsigned*)(gB + goff),
                (__attribute__((address_space(3))) unsigned*)(ldsB + idx * 8),
                16, 0, 0);
        }
        __syncthreads();   // vmcnt(0) drain at barrier -> staged data visible
        v8s af[4], bfv[4];
#pragma unroll
        for (int mt = 0; mt < 4; mt++)
            af[mt] = *(const v8s*)(lA + (wm + mt * 16 + l15) * 32 + quad * 8);
#pragma unroll
        for (int nt = 0; nt < 4; nt++)
            bfv[nt] = *(const v8s*)(lB + (wn + nt * 16 + l15) * 32 + quad * 8);
#pragma unroll
        for (int mt = 0; mt < 4; mt++)
#pragma unroll
            for (int nt = 0; nt < 4; nt++)
                acc[mt][nt] = __builtin_amdgcn_mfma_f32_16x16x32_bf16(
                    af[mt], bfv[nt], acc[mt][nt], 0, 0, 0);
    }
#pragma unroll
    for (int nt = 0; nt < 4; nt++) {
        int coln = n0 + wn + nt * 16 + l15;
        float bv = bias[coln];
#pragma unroll
        for (int mt = 0; mt < 4; mt++) {
            int rbase = m0 + wm + mt * 16 + quad * 4;
#pragma unroll
            for (int r = 0; r < 4; r++) {
                int row = rbase + r;
                int orow = mode ? ((row & 63) * 256 + (row >> 6)) : row;
                out[(size_t)orow * 1024 + coln] = acc[mt][nt][r] + bv;
            }
        }
    }
}

// ---------------------------------------------------------------------------
// K4: persistent recurrence — REVERTED VERBATIM to the session-best r0 kernel
// (787µs, flag protocol), sole change: tanh_fast (validated r6, same absmax).
// Six protocol variants (r1-r6: 860/1270/808/fail/866/1044) bracket a ~7400
// cy/step floor set by cross-XCD store->visibility + max-over-16 skew —
// protocol micro-structure is not the lever. Freeze this.
// ---------------------------------------------------------------------------
__global__ __launch_bounds__(256, 1) void rnn_step_all(
    const u16* __restrict__ wh_t, const float* __restrict__ bh,
    const float* __restrict__ ix, u64* __restrict__ h_buf64,  // [2][64][256] u64
    u16* __restrict__ h_all, float* __restrict__ out_tail,
    unsigned* __restrict__ flags) {                           // [257][4]
    const int tid = threadIdx.x, w = tid >> 6, lane = tid & 63;
    const int g = blockIdx.x, gb = g & 3, gc = g >> 2;
    const int quad = lane >> 4, l15 = lane & 15;
    const int col = gc * 64 + w * 16 + l15;
    __shared__ u16 hts[16 * 1032];   // 16 batches x 1024 (+8 pad) bf16

    // B fragments resident in registers: Wh^T[col][k]
    v8s bfr[32];
#pragma unroll
    for (int kc = 0; kc < 32; kc++)
        bfr[kc] = *(const v8s*)(wh_t + (size_t)col * 1024 + kc * 32 + quad * 8);
    const float bhv = bh[col];
    const int mrow0 = gb * 16 + quad * 4;   // this lane's 4 output batch rows
    const int srow = tid >> 4, sseg = tid & 15;   // staging role: 16 thr/row

    for (int t = 0; t < 256; t++) {
        // hoist ix_t loads above the poll to overlap their latency
        float ixv[4];
        {
            const float* ixp = ix + ((size_t)t * 64 + mrow0) * 1024 + col;
#pragma unroll
            for (int r = 0; r < 4; r++) ixv[r] = ixp[(size_t)r * 1024];
        }
        v4f acc = {0.f, 0.f, 0.f, 0.f};
        if (t > 0) {
            if (tid == 0) {   // single-lane poll of the one producer counter
                const unsigned* fp = flags + t * 4 + gb;
                int cnt = 0;
                while (__hip_atomic_load(fp, __ATOMIC_RELAXED,
                                         __HIP_MEMORY_SCOPE_AGENT) < 16u) {
                    if (++cnt > (1 << 20)) break;   // hang safety only
                }
            }
            __syncthreads();
            // stage h^t (our 16 batches, all 1024 cols) LDS via u64 atomics
            const u64* hsrc =
                h_buf64 + (size_t)(t & 1) * 16384 + (gb * 16 + srow) * 256;
            u64 tmp[16];
#pragma unroll
            for (int i = 0; i < 16; i++)
                tmp[i] = __hip_atomic_load(hsrc + sseg + i * 16,
                                           __ATOMIC_RELAXED,
                                           __HIP_MEMORY_SCOPE_AGENT);
#pragma unroll
            for (int i = 0; i < 16; i++)
                *(u64*)(hts + srow * 1032 + (sseg + i * 16) * 4) = tmp[i];
            __syncthreads();
#pragma unroll
            for (int kc = 0; kc < 32; kc++) {
                v8s a = *(const v8s*)(hts + l15 * 1032 + kc * 32 + quad * 8);
                acc = __builtin_amdgcn_mfma_f32_16x16x32_bf16(a, bfr[kc], acc,
                                                              0, 0, 0);
            }
        }
        // epilogue: h = tanh(acc + ix_t + bh)
        float hv[4]; u16 hb[4];
#pragma unroll
        for (int r = 0; r < 4; r++) {
            float pre = acc[r] + ixv[r] + bhv;
            hv[r] = tanh_fast(pre);
            hb[r] = f2bf(hv[r]);
        }
        // pack 4 adjacent cols -> u64 via DPP shuffles; atomic-store (sc0 sc1)
        u64* hdst = h_buf64 + (size_t)((t + 1) & 1) * 16384;
#pragma unroll
        for (int r = 0; r < 4; r++) {
            unsigned own = hb[r];
            unsigned other = __shfl_xor(own, 1);        // col^1 partner
            unsigned p = own | (other << 16);           // cols [c, c+1]
            unsigned p2 = __shfl_xor(p, 2);             // cols [c+2, c+3]
            if ((lane & 3) == 0) {
                u64 q = (u64)p | ((u64)p2 << 32);
                __hip_atomic_store(hdst + (mrow0 + r) * 256 + (col >> 2), q,
                                   __ATOMIC_RELAXED, __HIP_MEMORY_SCOPE_AGENT);
            }
        }
        __syncthreads();   // emits s_waitcnt vmcnt(0) before s_barrier:
                           // all 4 waves' sc1 stores acked at coherence point
        if (tid == 0)
            __hip_atomic_fetch_add(flags + (t + 1) * 4 + gb, 1u,
                                   __ATOMIC_RELAXED, __HIP_MEMORY_SCOPE_AGENT);
        // off the critical path: h_all (feeds Wo GEMM) + final hidden
        u16* hall = h_all + (size_t)t * 65536;
#pragma unroll
        for (int r = 0; r < 4; r++) {
            hall[(size_t)(mrow0 + r) * 1024 + col] = hb[r];
            if (t == 255) out_tail[(mrow0 + r) * 1024 + col] = hv[r];
        }
    }
}

// ---------------------------------------------------------------------------
// Workspace map (bytes):  [0,2M) Wi^T  [2M,4M) Wh^T  [4M,6M) Wo^T
// [6M,38M) Aemb bf16 (reused as h_all in phases 2/3)
// [38M,+256K) h parity buffers   [38.5M,+8K) flags
// ix (fp32 [T][B][H], 64MB) lives in d_out, consumed before phase 3 overwrites.
// ---------------------------------------------------------------------------
extern "C" void kernel_launch(void* const* d_in, const int* in_sizes, int n_in,
                              void* d_out, int out_size, void* d_ws,
                              size_t ws_size, hipStream_t stream) {
    const int*   input = (const int*)d_in[0];
    // d_in[1] = hidden (zeros by construction; t=0 path assumes h^0 = 0)
    const float* emb = (const float*)d_in[2];
    const float* Wi  = (const float*)d_in[3];
    const float* bi  = (const float*)d_in[4];
    const float* Wh  = (const float*)d_in[5];
    const float* bh  = (const float*)d_in[6];
    const float* Wo  = (const float*)d_in[7];
    const float* bo  = (const float*)d_in[8];
    float* out = (float*)d_out;
    char* ws = (char*)d_ws;

    u16* wi_t  = (u16*)(ws);
    u16* wh_t  = (u16*)(ws + (2ull << 20));
    u16* wo_t  = (u16*)(ws + (4ull << 20));
    u16* Aemb  = (u16*)(ws + (6ull << 20));            // 32MB, doubles as h_all
    u64* h_buf = (u64*)(ws + (38ull << 20));           // 256KB, [2][64][256] u64
    unsigned* flags = (unsigned*)(ws + (38ull << 20) + (512ull << 10)); // 8KB

    float* ix = out;                                   // [256][64][1024] fp32
    float* out_tail = out + 16777216ull;               // final hidden [64][1024]

    hipMemsetAsync(flags, 0, 8192, stream);
    convert_w<<<dim3(1024, 3), 256, 0, stream>>>(Wi, Wh, Wo, wi_t, wh_t, wo_t);
    gather_emb<<<4096, 256, 0, stream>>>(input, emb, Aemb);
    gemm_bias<<<dim3(128, 8), 256, 0, stream>>>(Aemb, wi_t, bi, ix, 0);
    rnn_step_all<<<64, 256, 0, stream>>>(wh_t, bh, ix, h_buf, Aemb, out_tail,
                                         flags);
    gemm_bias<<<dim3(128, 8), 256, 0, stream>>>(Aemb, wo_t, bo, out, 1);
}